// Round 1
// baseline (185.364 us; speedup 1.0000x reference)
//
#include <hip/hip_runtime.h>
#include <stdint.h>

typedef int i32x4  __attribute__((ext_vector_type(4)));
typedef int i32x16 __attribute__((ext_vector_type(16)));

static constexpr int Mdim   = 16384;     // B*S = 8*2048
static constexpr int Kdim   = 2048;      // D_IN
static constexpr int Ndim   = 2048;      // D_OUT
static constexpr int WELEMS = Ndim * Kdim;   // 4194304

// ---------------- async global->LDS (16B per lane, lane-ordered dest) -------
__device__ __forceinline__ void gload_lds16(const void* g, void* l) {
  __builtin_amdgcn_global_load_lds(
      (const __attribute__((address_space(1))) void*)g,
      (__attribute__((address_space(3))) void*)l,
      16, 0, 0);
}

// ---------------- K1: partial sums of |w| -----------------------------------
__global__ void k_abs_part(const float* __restrict__ w, float* __restrict__ part) {
  const float4* w4 = (const float4*)w;
  float s = 0.f;
  int idx = blockIdx.x * 256 + threadIdx.x;
  #pragma unroll 4
  for (int i = idx; i < WELEMS / 4; i += 256 * 256) {
    float4 v = w4[i];
    s += fabsf(v.x) + fabsf(v.y) + fabsf(v.z) + fabsf(v.w);
  }
  #pragma unroll
  for (int off = 32; off > 0; off >>= 1) s += __shfl_down(s, off);
  __shared__ float sm[4];
  if ((threadIdx.x & 63) == 0) sm[threadIdx.x >> 6] = s;
  __syncthreads();
  if (threadIdx.x == 0) part[blockIdx.x] = sm[0] + sm[1] + sm[2] + sm[3];
}

// ---------------- K2: finalize scale = mean(|w|) ----------------------------
__global__ void k_abs_final(const float* __restrict__ part, float* __restrict__ scal) {
  float s = part[threadIdx.x];           // exactly 256 partials, block = 256
  #pragma unroll
  for (int off = 32; off > 0; off >>= 1) s += __shfl_down(s, off);
  __shared__ float sm[4];
  if ((threadIdx.x & 63) == 0) sm[threadIdx.x >> 6] = s;
  __syncthreads();
  if (threadIdx.x == 0) scal[0] = (sm[0] + sm[1] + sm[2] + sm[3]) / (float)WELEMS;
}

// ---------------- K3: ternary weight quantize -------------------------------
__global__ void k_wquant(const float* __restrict__ w, char* __restrict__ wq,
                         const float* __restrict__ scal) {
  const float s = scal[0] + 1e-8f;
  const float4* w4 = (const float4*)w;
  const int idx = blockIdx.x * 256 + threadIdx.x;   // 262144 threads, 16 elems each
  int p[4];
  #pragma unroll
  for (int j = 0; j < 4; ++j) {
    float4 v = w4[idx * 4 + j];
    int q0 = (int)rintf(v.x / s); q0 = q0 < -1 ? -1 : (q0 > 1 ? 1 : q0);
    int q1 = (int)rintf(v.y / s); q1 = q1 < -1 ? -1 : (q1 > 1 ? 1 : q1);
    int q2 = (int)rintf(v.z / s); q2 = q2 < -1 ? -1 : (q2 > 1 ? 1 : q2);
    int q3 = (int)rintf(v.w / s); q3 = q3 < -1 ? -1 : (q3 > 1 ? 1 : q3);
    p[j] = (q0 & 255) | ((q1 & 255) << 8) | ((q2 & 255) << 16) | ((q3 & 255) << 24);
  }
  ((int4*)wq)[idx] = make_int4(p[0], p[1], p[2], p[3]);
}

// ---------------- K4: per-row activation absmax + int8 quantize -------------
__device__ __forceinline__ int quant4(float4 v, float sc) {
  int a = (int)rintf(v.x / sc); a = a < -128 ? -128 : (a > 127 ? 127 : a);
  int b = (int)rintf(v.y / sc); b = b < -128 ? -128 : (b > 127 ? 127 : b);
  int c = (int)rintf(v.z / sc); c = c < -128 ? -128 : (c > 127 ? 127 : c);
  int d = (int)rintf(v.w / sc); d = d < -128 ? -128 : (d > 127 ? 127 : d);
  return (a & 255) | ((b & 255) << 8) | ((c & 255) << 16) | ((d & 255) << 24);
}

__global__ void k_xquant(const float* __restrict__ x, char* __restrict__ xq,
                         float* __restrict__ xs) {
  const int row = blockIdx.x;            // 16384 rows
  const int tid = threadIdx.x;           // 256 threads, 8 floats each
  const float4* xr = (const float4*)(x + (size_t)row * Kdim);
  float4 v0 = xr[tid * 2];
  float4 v1 = xr[tid * 2 + 1];
  float m = fmaxf(fmaxf(fmaxf(fabsf(v0.x), fabsf(v0.y)), fmaxf(fabsf(v0.z), fabsf(v0.w))),
                  fmaxf(fmaxf(fabsf(v1.x), fabsf(v1.y)), fmaxf(fabsf(v1.z), fabsf(v1.w))));
  #pragma unroll
  for (int off = 1; off < 64; off <<= 1) m = fmaxf(m, __shfl_xor(m, off));
  __shared__ float sm[4];
  if ((tid & 63) == 0) sm[tid >> 6] = m;
  __syncthreads();
  float gm = fmaxf(fmaxf(sm[0], sm[1]), fmaxf(sm[2], sm[3]));
  gm = fmaxf(gm, 1e-8f);
  const float sc = gm / 127.0f;
  if (tid == 0) xs[row] = sc;
  ((int2*)(xq + (size_t)row * Kdim))[tid] = make_int2(quant4(v0, sc), quant4(v1, sc));
}

// ---------------- K5: int8 MFMA GEMM  out = (scale*xs[m]) * (xq . wq^T) + b -
// 128x128 tile, BK=64, 4 waves (2x2), each wave 64x64 = 2x2 mfma 32x32 tiles.
// LDS holds fragments in lane order: [rowgroup(32 rows)][ks(2)][lane*16B].
__global__ __launch_bounds__(256) void k_gemm(
    const char* __restrict__ xq, const char* __restrict__ wq,
    const float* __restrict__ xs, const float* __restrict__ scal,
    const float* __restrict__ bias, float* __restrict__ out) {
  __shared__ char Abuf[8192];
  __shared__ char Bbuf[8192];

  // XCD-aware bijective swizzle: 2048 blocks, 2048 % 8 == 0
  const int hw  = blockIdx.x;
  const int lin = (hw & 7) * 256 + (hw >> 3);
  const int bm  = lin >> 4;               // 128 M-tiles
  const int bn  = lin & 15;               // 16 N-tiles

  const int tid = threadIdx.x;
  const int w   = tid >> 6;
  const int l   = tid & 63;
  const int wr  = w >> 1, wc = w & 1;

  // staging source: wave w covers rows [w*32, w*32+32) of its tile,
  // lane l -> row (l&31), k-halfslot (l>>5)*16  => LDS byte = lane*16 exactly
  const size_t rowA = (size_t)(bm * 128 + w * 32 + (l & 31));
  const size_t rowB = (size_t)(bn * 128 + w * 32 + (l & 31));
  const int    ko   = (l >> 5) * 16;
  const char*  gA   = xq + rowA * Kdim + ko;
  const char*  gB   = wq + rowB * Kdim + ko;
  char* ldsA = Abuf + w * 2048;
  char* ldsB = Bbuf + w * 2048;

  i32x16 acc[2][2] = {};

  for (int kt = 0; kt < Kdim / 64; ++kt) {
    const int kb = kt * 64;
    gload_lds16(gA + kb,      ldsA);          // ks = 0
    gload_lds16(gA + kb + 32, ldsA + 1024);   // ks = 1
    gload_lds16(gB + kb,      ldsB);
    gload_lds16(gB + kb + 32, ldsB + 1024);
    __syncthreads();   // compiler drains vmcnt(0) before s_barrier

    i32x4 aF[2][2], bF[2][2];
    #pragma unroll
    for (int mi = 0; mi < 2; ++mi) {
      #pragma unroll
      for (int ks = 0; ks < 2; ++ks) {
        aF[mi][ks] = *(const i32x4*)(Abuf + ((wr * 2 + mi) * 2 + ks) * 1024 + l * 16);
        bF[mi][ks] = *(const i32x4*)(Bbuf + ((wc * 2 + mi) * 2 + ks) * 1024 + l * 16);
      }
    }
    #pragma unroll
    for (int mi = 0; mi < 2; ++mi)
      #pragma unroll
      for (int ni = 0; ni < 2; ++ni)
        #pragma unroll
        for (int ks = 0; ks < 2; ++ks)
          acc[mi][ni] = __builtin_amdgcn_mfma_i32_32x32x32_i8(
              aF[mi][ks], bF[ni][ks], acc[mi][ni], 0, 0, 0);
    __syncthreads();
  }

  // epilogue: C/D mapping col = lane&31, row = (r&3) + 8*(r>>2) + 4*(lane>>5)
  const float wsc = scal[0];
  #pragma unroll
  for (int mi = 0; mi < 2; ++mi) {
    const int r0 = bm * 128 + wr * 64 + mi * 32 + 4 * (l >> 5);
    #pragma unroll
    for (int ni = 0; ni < 2; ++ni) {
      const int col  = bn * 128 + wc * 64 + ni * 32 + (l & 31);
      const float bc = bias[col];
      #pragma unroll
      for (int r = 0; r < 16; ++r) {
        const int row = r0 + (r & 3) + 8 * (r >> 2);
        out[(size_t)row * Ndim + col] = (float)acc[mi][ni][r] * (wsc * xs[row]) + bc;
      }
    }
  }
}

// ---------------- launch -----------------------------------------------------
extern "C" void kernel_launch(void* const* d_in, const int* in_sizes, int n_in,
                              void* d_out, int out_size, void* d_ws, size_t ws_size,
                              hipStream_t stream) {
  const float* x    = (const float*)d_in[0];
  const float* wgt  = (const float*)d_in[1];
  const float* bias = (const float*)d_in[2];
  float* out = (float*)d_out;

  float* ws_f = (float*)d_ws;
  float* scal = ws_f;               // 1 float
  float* part = ws_f + 64;          // 256 floats
  float* xs   = ws_f + 1024;        // 16384 floats
  char*  wq   = (char*)(ws_f + 20480);          // 4 MiB, 16B-aligned
  char*  xq   = wq + (size_t)WELEMS;            // 32 MiB, 16B-aligned

  hipLaunchKernelGGL(k_abs_part,  dim3(256),          dim3(256), 0, stream, wgt, part);
  hipLaunchKernelGGL(k_abs_final, dim3(1),            dim3(256), 0, stream, part, scal);
  hipLaunchKernelGGL(k_wquant,    dim3(WELEMS/4096),  dim3(256), 0, stream, wgt, wq, scal);
  hipLaunchKernelGGL(k_xquant,    dim3(Mdim),         dim3(256), 0, stream, x, xq, xs);
  hipLaunchKernelGGL(k_gemm,      dim3((Mdim/128)*(Ndim/128)), dim3(256), 0, stream,
                     xq, wq, xs, scal, bias, out);
}

// Round 2
// 163.579 us; speedup vs baseline: 1.1332x; 1.1332x over previous
//
#include <hip/hip_runtime.h>
#include <stdint.h>

typedef int i32x4  __attribute__((ext_vector_type(4)));
typedef int i32x16 __attribute__((ext_vector_type(16)));

static constexpr int Mdim   = 16384;     // B*S = 8*2048
static constexpr int Kdim   = 2048;      // D_IN
static constexpr int Ndim   = 2048;      // D_OUT
static constexpr int WELEMS = Ndim * Kdim;   // 4194304

// ---------------- async global->LDS (16B per lane, lane-ordered dest) -------
__device__ __forceinline__ void gload_lds16(const void* g, void* l) {
  __builtin_amdgcn_global_load_lds(
      (const __attribute__((address_space(1))) void*)g,
      (__attribute__((address_space(3))) void*)l,
      16, 0, 0);
}

// ---------------- K1: partial sums of |w| -----------------------------------
__global__ void k_abs_part(const float* __restrict__ w, float* __restrict__ part) {
  const float4* w4 = (const float4*)w;
  float s = 0.f;
  int idx = blockIdx.x * 256 + threadIdx.x;
  #pragma unroll 4
  for (int i = idx; i < WELEMS / 4; i += 256 * 256) {
    float4 v = w4[i];
    s += fabsf(v.x) + fabsf(v.y) + fabsf(v.z) + fabsf(v.w);
  }
  #pragma unroll
  for (int off = 32; off > 0; off >>= 1) s += __shfl_down(s, off);
  __shared__ float sm[4];
  if ((threadIdx.x & 63) == 0) sm[threadIdx.x >> 6] = s;
  __syncthreads();
  if (threadIdx.x == 0) part[blockIdx.x] = sm[0] + sm[1] + sm[2] + sm[3];
}

// ---------------- K2: finalize scale = mean(|w|) ----------------------------
__global__ void k_abs_final(const float* __restrict__ part, float* __restrict__ scal) {
  float s = part[threadIdx.x];           // exactly 256 partials, block = 256
  #pragma unroll
  for (int off = 32; off > 0; off >>= 1) s += __shfl_down(s, off);
  __shared__ float sm[4];
  if ((threadIdx.x & 63) == 0) sm[threadIdx.x >> 6] = s;
  __syncthreads();
  if (threadIdx.x == 0) scal[0] = (sm[0] + sm[1] + sm[2] + sm[3]) / (float)WELEMS;
}

// ---------------- K3: ternary weight quantize -------------------------------
__global__ void k_wquant(const float* __restrict__ w, char* __restrict__ wq,
                         const float* __restrict__ scal) {
  const float s = scal[0] + 1e-8f;
  const float4* w4 = (const float4*)w;
  const int idx = blockIdx.x * 256 + threadIdx.x;   // 262144 threads, 16 elems each
  int p[4];
  #pragma unroll
  for (int j = 0; j < 4; ++j) {
    float4 v = w4[idx * 4 + j];
    int q0 = (int)rintf(v.x / s); q0 = q0 < -1 ? -1 : (q0 > 1 ? 1 : q0);
    int q1 = (int)rintf(v.y / s); q1 = q1 < -1 ? -1 : (q1 > 1 ? 1 : q1);
    int q2 = (int)rintf(v.z / s); q2 = q2 < -1 ? -1 : (q2 > 1 ? 1 : q2);
    int q3 = (int)rintf(v.w / s); q3 = q3 < -1 ? -1 : (q3 > 1 ? 1 : q3);
    p[j] = (q0 & 255) | ((q1 & 255) << 8) | ((q2 & 255) << 16) | ((q3 & 255) << 24);
  }
  ((int4*)wq)[idx] = make_int4(p[0], p[1], p[2], p[3]);
}

// ---------------- K4: per-row activation absmax + int8 quantize -------------
__device__ __forceinline__ int quant4(float4 v, float sc) {
  int a = (int)rintf(v.x / sc); a = a < -128 ? -128 : (a > 127 ? 127 : a);
  int b = (int)rintf(v.y / sc); b = b < -128 ? -128 : (b > 127 ? 127 : b);
  int c = (int)rintf(v.z / sc); c = c < -128 ? -128 : (c > 127 ? 127 : c);
  int d = (int)rintf(v.w / sc); d = d < -128 ? -128 : (d > 127 ? 127 : d);
  return (a & 255) | ((b & 255) << 8) | ((c & 255) << 16) | ((d & 255) << 24);
}

__global__ void k_xquant(const float* __restrict__ x, char* __restrict__ xq,
                         float* __restrict__ xs) {
  const int row = blockIdx.x;            // 16384 rows
  const int tid = threadIdx.x;           // 256 threads, 8 floats each
  const float4* xr = (const float4*)(x + (size_t)row * Kdim);
  float4 v0 = xr[tid * 2];
  float4 v1 = xr[tid * 2 + 1];
  float m = fmaxf(fmaxf(fmaxf(fabsf(v0.x), fabsf(v0.y)), fmaxf(fabsf(v0.z), fabsf(v0.w))),
                  fmaxf(fmaxf(fabsf(v1.x), fabsf(v1.y)), fmaxf(fabsf(v1.z), fabsf(v1.w))));
  #pragma unroll
  for (int off = 1; off < 64; off <<= 1) m = fmaxf(m, __shfl_xor(m, off));
  __shared__ float sm[4];
  if ((tid & 63) == 0) sm[tid >> 6] = m;
  __syncthreads();
  float gm = fmaxf(fmaxf(sm[0], sm[1]), fmaxf(sm[2], sm[3]));
  gm = fmaxf(gm, 1e-8f);
  const float sc = gm / 127.0f;
  if (tid == 0) xs[row] = sc;
  ((int2*)(xq + (size_t)row * Kdim))[tid] = make_int2(quant4(v0, sc), quant4(v1, sc));
}

// ---------------- K5: int8 MFMA GEMM, 256x256 tile, BK=128, 2-phase prefetch
// out = (scale*xs[m]) * (xq . wq^T) + bias
// 8 waves (2M x 4N), wave tile 128x64 = acc[4][2] of 32x32.
// LDS fragment-ordered: byte ((rg*4+ks)*64 + lane)*16 holds
//   row = rg*32 + (lane&31), k = ks*32 + (lane>>5)*16  (16 contiguous bytes)
__global__ __launch_bounds__(512, 2) void k_gemm(
    const char* __restrict__ xq, const char* __restrict__ wq,
    const float* __restrict__ xs, const float* __restrict__ scal,
    const float* __restrict__ bias, float* __restrict__ out) {
  __shared__ char Abuf[2][32768];
  __shared__ char Bbuf[2][32768];

  // XCD-aware bijective swizzle: 512 blocks, 512 % 8 == 0
  const int hw  = blockIdx.x;
  const int lin = (hw & 7) * 64 + (hw >> 3);
  const int bm  = lin >> 3;               // 64 M-tiles
  const int bn  = lin & 7;                // 8 N-tiles

  const int tid = threadIdx.x;
  const int w   = tid >> 6;               // wave 0..7
  const int l   = tid & 63;
  const int wr  = w >> 2, wc = w & 3;     // 2 x 4 wave grid
  const int l16 = l * 16;

  // staging: wave w, load j in [0,4):
  //   LDS idx16 = j*512 + w*64 + lane  ->  rg = j*2 + (w>>2), ks = w&3
  //   row = j*64 + (w>>2)*32 + (l&31),  k = (w&3)*32 + (l>>5)*16
  const int    srow = (w >> 2) * 32 + (l & 31);
  const int    sk   = (w & 3) * 32 + (l >> 5) * 16;
  const char*  gA   = xq + (size_t)(bm * 256 + srow) * Kdim + sk;
  const char*  gB   = wq + (size_t)(bn * 256 + srow) * Kdim + sk;
  const int    ldsb = w * 1024;           // + j*8192, lane*16 added by HW

#define STAGE(c, kb)                                                     \
  {                                                                      \
    _Pragma("unroll")                                                    \
    for (int j = 0; j < 4; ++j)                                          \
      gload_lds16(gA + (size_t)j * 64 * Kdim + (kb), &Abuf[c][j * 8192 + ldsb]); \
    _Pragma("unroll")                                                    \
    for (int j = 0; j < 4; ++j)                                          \
      gload_lds16(gB + (size_t)j * 64 * Kdim + (kb), &Bbuf[c][j * 8192 + ldsb]); \
  }

  i32x16 acc[4][2] = {};
  int cur = 0;

  STAGE(0, 0);
  __syncthreads();

  for (int kt = 0; kt < Kdim / 128; ++kt) {       // 16 K-tiles
    if (kt < Kdim / 128 - 1) STAGE(cur ^ 1, (kt + 1) * 128);

    // B fragments for the whole K-tile (held across both phases)
    i32x4 bF[2][4];
    #pragma unroll
    for (int ni = 0; ni < 2; ++ni)
      #pragma unroll
      for (int ks = 0; ks < 4; ++ks)
        bF[ni][ks] = *(const i32x4*)(&Bbuf[cur][((wc * 2 + ni) * 4 + ks) * 1024 + l16]);

    // ---- phase A: mi = 0,1 ----
    {
      i32x4 aF[2][4];
      #pragma unroll
      for (int mi = 0; mi < 2; ++mi)
        #pragma unroll
        for (int ks = 0; ks < 4; ++ks)
          aF[mi][ks] = *(const i32x4*)(&Abuf[cur][((wr * 4 + mi) * 4 + ks) * 1024 + l16]);
      __builtin_amdgcn_s_setprio(1);
      #pragma unroll
      for (int mi = 0; mi < 2; ++mi)
        #pragma unroll
        for (int ni = 0; ni < 2; ++ni)
          #pragma unroll
          for (int ks = 0; ks < 4; ++ks)
            acc[mi][ni] = __builtin_amdgcn_mfma_i32_32x32x32_i8(
                aF[mi][ks], bF[ni][ks], acc[mi][ni], 0, 0, 0);
      __builtin_amdgcn_s_setprio(0);
    }
    __builtin_amdgcn_s_barrier();   // cohesion only (no data hazard here)

    // ---- phase B: mi = 2,3 ----
    {
      i32x4 aF[2][4];
      #pragma unroll
      for (int mi = 0; mi < 2; ++mi)
        #pragma unroll
        for (int ks = 0; ks < 4; ++ks)
          aF[mi][ks] = *(const i32x4*)(&Abuf[cur][((wr * 4 + mi + 2) * 4 + ks) * 1024 + l16]);
      __builtin_amdgcn_s_setprio(1);
      #pragma unroll
      for (int mi = 0; mi < 2; ++mi)
        #pragma unroll
        for (int ni = 0; ni < 2; ++ni)
          #pragma unroll
          for (int ks = 0; ks < 4; ++ks)
            acc[mi + 2][ni] = __builtin_amdgcn_mfma_i32_32x32x32_i8(
                aF[mi][ks], bF[ni][ks], acc[mi + 2][ni], 0, 0, 0);
      __builtin_amdgcn_s_setprio(0);
    }
    __syncthreads();                // drains vmcnt(0): next buffer ready
    cur ^= 1;
  }
#undef STAGE

  // epilogue: C/D mapping col = lane&31, row = (r&3) + 8*(r>>2) + 4*(lane>>5)
  const float wsc = scal[0];
  const int   lhi = (l >> 5) * 4, lcol = l & 31;
  float bc[2];
  #pragma unroll
  for (int ni = 0; ni < 2; ++ni)
    bc[ni] = bias[bn * 256 + wc * 64 + ni * 32 + lcol];

  #pragma unroll
  for (int mi = 0; mi < 4; ++mi) {
    const int rb = bm * 256 + wr * 128 + mi * 32 + lhi;
    #pragma unroll
    for (int r = 0; r < 16; ++r) {
      const int   row = rb + (r & 3) + 8 * (r >> 2);
      const float sv  = wsc * xs[row];
      #pragma unroll
      for (int ni = 0; ni < 2; ++ni) {
        const int col = bn * 256 + wc * 64 + ni * 32 + lcol;
        out[(size_t)row * Ndim + col] = (float)acc[mi][ni][r] * sv + bc[ni];
      }
    }
  }
}

// ---------------- launch -----------------------------------------------------
extern "C" void kernel_launch(void* const* d_in, const int* in_sizes, int n_in,
                              void* d_out, int out_size, void* d_ws, size_t ws_size,
                              hipStream_t stream) {
  const float* x    = (const float*)d_in[0];
  const float* wgt  = (const float*)d_in[1];
  const float* bias = (const float*)d_in[2];
  float* out = (float*)d_out;

  float* ws_f = (float*)d_ws;
  float* scal = ws_f;               // 1 float
  float* part = ws_f + 64;          // 256 floats
  float* xs   = ws_f + 1024;        // 16384 floats
  char*  wq   = (char*)(ws_f + 20480);          // 4 MiB, 16B-aligned
  char*  xq   = wq + (size_t)WELEMS;            // 32 MiB, 16B-aligned

  hipLaunchKernelGGL(k_abs_part,  dim3(256),          dim3(256), 0, stream, wgt, part);
  hipLaunchKernelGGL(k_abs_final, dim3(1),            dim3(256), 0, stream, part, scal);
  hipLaunchKernelGGL(k_wquant,    dim3(WELEMS/4096),  dim3(256), 0, stream, wgt, wq, scal);
  hipLaunchKernelGGL(k_xquant,    dim3(Mdim),         dim3(256), 0, stream, x, xq, xs);
  hipLaunchKernelGGL(k_gemm,      dim3((Mdim/256)*(Ndim/256)), dim3(512), 0, stream,
                     xq, wq, xs, scal, bias, out);
}

// Round 4
// 137.926 us; speedup vs baseline: 1.3439x; 1.1860x over previous
//
#include <hip/hip_runtime.h>
#include <stdint.h>

typedef int i32x4  __attribute__((ext_vector_type(4)));
typedef int i32x16 __attribute__((ext_vector_type(16)));

static constexpr int Mdim   = 16384;     // B*S = 8*2048
static constexpr int Kdim   = 2048;      // D_IN
static constexpr int Ndim   = 2048;      // D_OUT
static constexpr int WELEMS = Ndim * Kdim;   // 4194304

// ---------------- async global->LDS (16B per lane, lane-ordered dest) -------
__device__ __forceinline__ void gload_lds16(const void* g, void* l) {
  __builtin_amdgcn_global_load_lds(
      (const __attribute__((address_space(1))) void*)g,
      (__attribute__((address_space(3))) void*)l,
      16, 0, 0);
}

// ---------------- K1: partial sums of |w| -----------------------------------
__global__ void k_abs_part(const float* __restrict__ w, float* __restrict__ part) {
  const float4* w4 = (const float4*)w;
  float s = 0.f;
  int idx = blockIdx.x * 256 + threadIdx.x;
  #pragma unroll 4
  for (int i = idx; i < WELEMS / 4; i += 256 * 256) {
    float4 v = w4[i];
    s += fabsf(v.x) + fabsf(v.y) + fabsf(v.z) + fabsf(v.w);
  }
  #pragma unroll
  for (int off = 32; off > 0; off >>= 1) s += __shfl_down(s, off);
  __shared__ float sm[4];
  if ((threadIdx.x & 63) == 0) sm[threadIdx.x >> 6] = s;
  __syncthreads();
  if (threadIdx.x == 0) part[blockIdx.x] = sm[0] + sm[1] + sm[2] + sm[3];
}

// ---------------- K2: finalize scale = mean(|w|) ----------------------------
__global__ void k_abs_final(const float* __restrict__ part, float* __restrict__ scal) {
  float s = part[threadIdx.x];           // exactly 256 partials, block = 256
  #pragma unroll
  for (int off = 32; off > 0; off >>= 1) s += __shfl_down(s, off);
  __shared__ float sm[4];
  if ((threadIdx.x & 63) == 0) sm[threadIdx.x >> 6] = s;
  __syncthreads();
  if (threadIdx.x == 0) scal[0] = (sm[0] + sm[1] + sm[2] + sm[3]) / (float)WELEMS;
}

// ---------------- K3: ternary weight quantize -------------------------------
__global__ void k_wquant(const float* __restrict__ w, char* __restrict__ wq,
                         const float* __restrict__ scal) {
  const float s = scal[0] + 1e-8f;
  const float4* w4 = (const float4*)w;
  const int idx = blockIdx.x * 256 + threadIdx.x;   // 262144 threads, 16 elems each
  int p[4];
  #pragma unroll
  for (int j = 0; j < 4; ++j) {
    float4 v = w4[idx * 4 + j];
    int q0 = (int)rintf(v.x / s); q0 = q0 < -1 ? -1 : (q0 > 1 ? 1 : q0);
    int q1 = (int)rintf(v.y / s); q1 = q1 < -1 ? -1 : (q1 > 1 ? 1 : q1);
    int q2 = (int)rintf(v.z / s); q2 = q2 < -1 ? -1 : (q2 > 1 ? 1 : q2);
    int q3 = (int)rintf(v.w / s); q3 = q3 < -1 ? -1 : (q3 > 1 ? 1 : q3);
    p[j] = (q0 & 255) | ((q1 & 255) << 8) | ((q2 & 255) << 16) | ((q3 & 255) << 24);
  }
  ((int4*)wq)[idx] = make_int4(p[0], p[1], p[2], p[3]);
}

// ---------------- K4: per-row activation absmax + int8 quantize -------------
__device__ __forceinline__ int quant4(float4 v, float sc) {
  int a = (int)rintf(v.x / sc); a = a < -128 ? -128 : (a > 127 ? 127 : a);
  int b = (int)rintf(v.y / sc); b = b < -128 ? -128 : (b > 127 ? 127 : b);
  int c = (int)rintf(v.z / sc); c = c < -128 ? -128 : (c > 127 ? 127 : c);
  int d = (int)rintf(v.w / sc); d = d < -128 ? -128 : (d > 127 ? 127 : d);
  return (a & 255) | ((b & 255) << 8) | ((c & 255) << 16) | ((d & 255) << 24);
}

__global__ void k_xquant(const float* __restrict__ x, char* __restrict__ xq,
                         float* __restrict__ xs) {
  const int row = blockIdx.x;            // 16384 rows
  const int tid = threadIdx.x;           // 256 threads, 8 floats each
  const float4* xr = (const float4*)(x + (size_t)row * Kdim);
  float4 v0 = xr[tid * 2];
  float4 v1 = xr[tid * 2 + 1];
  float m = fmaxf(fmaxf(fmaxf(fabsf(v0.x), fabsf(v0.y)), fmaxf(fabsf(v0.z), fabsf(v0.w))),
                  fmaxf(fmaxf(fabsf(v1.x), fabsf(v1.y)), fmaxf(fabsf(v1.z), fabsf(v1.w))));
  #pragma unroll
  for (int off = 1; off < 64; off <<= 1) m = fmaxf(m, __shfl_xor(m, off));
  __shared__ float sm[4];
  if ((tid & 63) == 0) sm[tid >> 6] = m;
  __syncthreads();
  float gm = fmaxf(fmaxf(sm[0], sm[1]), fmaxf(sm[2], sm[3]));
  gm = fmaxf(gm, 1e-8f);
  const float sc = gm / 127.0f;
  if (tid == 0) xs[row] = sc;
  ((int2*)(xq + (size_t)row * Kdim))[tid] = make_int2(quant4(v0, sc), quant4(v1, sc));
}

// ---------------- K5: int8 MFMA GEMM, 256x256 tile, BK=64, 4-buf ring -------
// out = (scale*xs[m]) * (xq . wq^T) + bias
// 8 waves (2M x 4N), wave tile 128x64 = acc[4][2] of 32x32 mfma.
// Counted-vmcnt pipeline: prefetch 3 K-tiles ahead, s_waitcnt vmcnt(8) +
// raw s_barrier once per K-tile; vmcnt never drains to 0 in the main loop.
// LDS fragment-ordered (zero bank conflicts): buffer b (32 KiB) holds
//   A at +0, B at +16384; 16B chunk (rg*2+ks)*1024 + lane*16 holds
//   row = rg*32 + (lane&31), k = ks*32 + (lane>>5)*16.
__global__ __launch_bounds__(512, 2) void k_gemm(
    const char* __restrict__ xq, const char* __restrict__ wq,
    const float* __restrict__ xs, const float* __restrict__ scal,
    const float* __restrict__ bias, float* __restrict__ out) {
  __shared__ __attribute__((aligned(128))) char lds[4][32768];

  // XCD-aware bijective swizzle: 512 blocks, 512 % 8 == 0.
  // All 8 bn-blocks of one bm-panel land on the same XCD -> A panel in L2 once.
  const int hw  = blockIdx.x;
  const int lin = (hw & 7) * 64 + (hw >> 3);
  const int bm  = lin >> 3;               // 64 M-tiles
  const int bn  = lin & 7;                // 8 N-tiles

  const int tid = threadIdx.x;
  const int w   = tid >> 6;               // wave 0..7
  const int l   = tid & 63;
  const int wr  = w >> 2, wc = w & 3;     // 2 x 4 wave grid
  const int l16 = l * 16;

  // staging: wave w stages rg = w (rows w*32..w*32+31), ks in {0,1}
  const char* gA = xq + (size_t)(bm * 256 + w * 32 + (l & 31)) * Kdim + ((l >> 5) * 16);
  const char* gB = wq + (size_t)(bn * 256 + w * 32 + (l & 31)) * Kdim + ((l >> 5) * 16);
  const int   w2k = w * 2048;             // (w*2)*1024

#define STAGE(t_)                                                         \
  {                                                                       \
    char* sb = &lds[(t_) & 3][0];                                         \
    const int kb_ = (t_) * 64;                                            \
    gload_lds16(gA + kb_,      sb + w2k);                                 \
    gload_lds16(gA + kb_ + 32, sb + w2k + 1024);                          \
    gload_lds16(gB + kb_,      sb + 16384 + w2k);                         \
    gload_lds16(gB + kb_ + 32, sb + 16384 + w2k + 1024);                  \
  }

  i32x16 acc[4][2] = {};

  STAGE(0); STAGE(1); STAGE(2);           // 12 loads in flight

  #pragma unroll 4
  for (int t = 0; t < Kdim / 64; ++t) {   // 32 K-tiles
    // tile t landed iff outstanding <= 8 (tiles t+1, t+2 = 8 newer loads)
    asm volatile("s_waitcnt vmcnt(8)" ::: "memory");
    __builtin_amdgcn_s_barrier();
    asm volatile("" ::: "memory");        // no LDS reads hoist above barrier

    if (t + 3 < Kdim / 64) STAGE(t + 3);  // into buf[(t-1)&3], freed by barrier

    const char* base = &lds[t & 3][0];
    i32x4 aF[4][2], bF[2][2];
    #pragma unroll
    for (int mi = 0; mi < 4; ++mi)
      #pragma unroll
      for (int ks = 0; ks < 2; ++ks)
        aF[mi][ks] = *(const i32x4*)(base + ((wr * 4 + mi) * 2 + ks) * 1024 + l16);
    #pragma unroll
    for (int ni = 0; ni < 2; ++ni)
      #pragma unroll
      for (int ks = 0; ks < 2; ++ks)
        bF[ni][ks] = *(const i32x4*)(base + 16384 + ((wc * 2 + ni) * 2 + ks) * 1024 + l16);

    __builtin_amdgcn_s_setprio(1);
    #pragma unroll
    for (int ks = 0; ks < 2; ++ks)        // ks outer: dep-chain distance 8
      #pragma unroll
      for (int mi = 0; mi < 4; ++mi)
        #pragma unroll
        for (int ni = 0; ni < 2; ++ni)
          acc[mi][ni] = __builtin_amdgcn_mfma_i32_32x32x32_i8(
              aF[mi][ks], bF[ni][ks], acc[mi][ni], 0, 0, 0);
    __builtin_amdgcn_s_setprio(0);
  }
#undef STAGE

  // epilogue: C/D mapping col = lane&31, row = (r&3) + 8*(r>>2) + 4*(lane>>5)
  const float wsc = scal[0];
  const int   lhi = (l >> 5) * 4, lcol = l & 31;
  float bc[2];
  #pragma unroll
  for (int ni = 0; ni < 2; ++ni)
    bc[ni] = bias[bn * 256 + wc * 64 + ni * 32 + lcol];

  #pragma unroll
  for (int mi = 0; mi < 4; ++mi) {
    const int rb = bm * 256 + wr * 128 + mi * 32 + lhi;
    #pragma unroll
    for (int r = 0; r < 16; ++r) {
      const int   row = rb + (r & 3) + 8 * (r >> 2);
      const float sv  = wsc * xs[row];
      #pragma unroll
      for (int ni = 0; ni < 2; ++ni) {
        const int col = bn * 256 + wc * 64 + ni * 32 + lcol;
        out[(size_t)row * Ndim + col] = (float)acc[mi][ni][r] * sv + bc[ni];
      }
    }
  }
}

// ---------------- launch -----------------------------------------------------
extern "C" void kernel_launch(void* const* d_in, const int* in_sizes, int n_in,
                              void* d_out, int out_size, void* d_ws, size_t ws_size,
                              hipStream_t stream) {
  const float* x    = (const float*)d_in[0];
  const float* wgt  = (const float*)d_in[1];
  const float* bias = (const float*)d_in[2];
  float* out = (float*)d_out;

  float* ws_f = (float*)d_ws;
  float* scal = ws_f;               // 1 float
  float* part = ws_f + 64;          // 256 floats
  float* xs   = ws_f + 1024;        // 16384 floats
  char*  wq   = (char*)(ws_f + 20480);          // 4 MiB, 16B-aligned
  char*  xq   = wq + (size_t)WELEMS;            // 32 MiB, 16B-aligned

  hipLaunchKernelGGL(k_abs_part,  dim3(256),          dim3(256), 0, stream, wgt, part);
  hipLaunchKernelGGL(k_abs_final, dim3(1),            dim3(256), 0, stream, part, scal);
  hipLaunchKernelGGL(k_wquant,    dim3(WELEMS/4096),  dim3(256), 0, stream, wgt, wq, scal);
  hipLaunchKernelGGL(k_xquant,    dim3(Mdim),         dim3(256), 0, stream, x, xq, xs);
  hipLaunchKernelGGL(k_gemm,      dim3((Mdim/256)*(Ndim/256)), dim3(512), 0, stream,
                     xq, wq, xs, scal, bias, out);
}